// Round 3
// baseline (1024.182 us; speedup 1.0000x reference)
//
#include <hip/hip_runtime.h>
#include <math.h>

#define B_  2
#define S_  1024
#define H_  2048
#define F_  512          // H/4
#define KD_ 32
#define NC_ 16
#define M_  2048         // B*S tokens
#define NPROJ 184        // 4+12+40+128 packed u-rows
#define LDP 192          // proj row stride

typedef __attribute__((ext_vector_type(8))) short bf16x8;
typedef __attribute__((ext_vector_type(4))) float f32x4;

__device__ __forceinline__ ushort f2bf(float f) {
    unsigned u = __float_as_uint(f);
    u += 0x7FFFu + ((u >> 16) & 1u);   // RNE
    return (ushort)(u >> 16);
}
__device__ __forceinline__ float bf2f(ushort h) {
    return __uint_as_float(((unsigned)h) << 16);
}
__device__ __forceinline__ uint4 pack_hi8(float4 a, float4 b) {
    uint4 r;
    r.x = (unsigned)f2bf(a.x) | ((unsigned)f2bf(a.y) << 16);
    r.y = (unsigned)f2bf(a.z) | ((unsigned)f2bf(a.w) << 16);
    r.z = (unsigned)f2bf(b.x) | ((unsigned)f2bf(b.y) << 16);
    r.w = (unsigned)f2bf(b.z) | ((unsigned)f2bf(b.w) << 16);
    return r;
}
__device__ __forceinline__ void pack_hilo8(float4 a, float4 b, uint4* hi, uint4* lo) {
    float v[8] = {a.x, a.y, a.z, a.w, b.x, b.y, b.z, b.w};
    unsigned h[8], l[8];
#pragma unroll
    for (int i = 0; i < 8; ++i) {
        ushort hh = f2bf(v[i]);
        h[i] = hh;
        l[i] = f2bf(v[i] - bf2f(hh));
    }
    *hi = make_uint4(h[0] | (h[1] << 16), h[2] | (h[3] << 16),
                     h[4] | (h[5] << 16), h[6] | (h[7] << 16));
    *lo = make_uint4(l[0] | (l[1] << 16), l[2] | (l[3] << 16),
                     l[4] | (l[5] << 16), l[6] | (l[7] << 16));
}

// ---------------------------------------------------------------------------
// conv_kernel: bf16 conversions + pool partials, one pass.
// blocks 0..127    : x rows blk*16..+16 -> xhi,xlo + column-sum partial[blk]
// blocks 128..1151 : lw (flat, hi only)
// blocks 1152..1407: sw1 (flat, hi+lo)
// blocks 1408..1499: u4|u12|u40|u128 -> packed ubh rows {0,4,16,56}
// ---------------------------------------------------------------------------
__global__ __launch_bounds__(256) void conv_kernel(
    const float* __restrict__ x, const float* __restrict__ lw,
    const float* __restrict__ sw1,
    const float* __restrict__ u4, const float* __restrict__ u12,
    const float* __restrict__ u40, const float* __restrict__ u128,
    ushort* __restrict__ xhi, ushort* __restrict__ xlo,
    ushort* __restrict__ lwh, ushort* __restrict__ swh,
    ushort* __restrict__ swl, ushort* __restrict__ ubh,
    float* __restrict__ partial) {
    int blk = blockIdx.x, tid = threadIdx.x;
    if (blk < 128) {
        int c0 = tid << 3;
        float cs0 = 0.f, cs1 = 0.f, cs2 = 0.f, cs3 = 0.f;
        float cs4 = 0.f, cs5 = 0.f, cs6 = 0.f, cs7 = 0.f;
        for (int r = 0; r < 16; ++r) {
            size_t off = (size_t)(blk * 16 + r) * H_ + c0;
            float4 a = *(const float4*)(x + off);
            float4 b = *(const float4*)(x + off + 4);
            cs0 += a.x; cs1 += a.y; cs2 += a.z; cs3 += a.w;
            cs4 += b.x; cs5 += b.y; cs6 += b.z; cs7 += b.w;
            uint4 hi, lo;
            pack_hilo8(a, b, &hi, &lo);
            *(uint4*)(xhi + off) = hi;
            *(uint4*)(xlo + off) = lo;
        }
        float* pr = partial + (size_t)blk * H_ + c0;
        pr[0] = cs0; pr[1] = cs1; pr[2] = cs2; pr[3] = cs3;
        pr[4] = cs4; pr[5] = cs5; pr[6] = cs6; pr[7] = cs7;
    } else if (blk < 1152) {
        size_t base = (size_t)(blk - 128) * 4096 + (size_t)tid * 16;
#pragma unroll
        for (int q = 0; q < 2; ++q) {
            size_t o = base + q * 8;
            float4 a = *(const float4*)(lw + o);
            float4 b = *(const float4*)(lw + o + 4);
            *(uint4*)(lwh + o) = pack_hi8(a, b);
        }
    } else if (blk < 1408) {
        size_t base = (size_t)(blk - 1152) * 4096 + (size_t)tid * 16;
#pragma unroll
        for (int q = 0; q < 2; ++q) {
            size_t o = base + q * 8;
            float4 a = *(const float4*)(sw1 + o);
            float4 b = *(const float4*)(sw1 + o + 4);
            uint4 hi, lo;
            pack_hilo8(a, b, &hi, &lo);
            *(uint4*)(swh + o) = hi;
            *(uint4*)(swl + o) = lo;
        }
    } else {
        const float* src; ushort* dst; int rel;
        if (blk < 1410)      { src = u4;   dst = ubh;            rel = blk - 1408; }
        else if (blk < 1416) { src = u12;  dst = ubh + 4 * H_;   rel = blk - 1410; }
        else if (blk < 1436) { src = u40;  dst = ubh + 16 * H_;  rel = blk - 1416; }
        else                 { src = u128; dst = ubh + 56 * H_;  rel = blk - 1436; }
        size_t base = (size_t)rel * 4096 + (size_t)tid * 16;
#pragma unroll
        for (int q = 0; q < 2; ++q) {
            size_t o = base + q * 8;
            float4 a = *(const float4*)(src + o);
            float4 b = *(const float4*)(src + o + 4);
            *(uint4*)(dst + o) = pack_hi8(a, b);
        }
    }
}

// ---------------------------------------------------------------------------
// pool_final: xp[b][col] = mean over S of x -> from 64 partials per b.
// ---------------------------------------------------------------------------
__global__ __launch_bounds__(256) void pool_final_kernel(
    const float* __restrict__ partial, float* __restrict__ xp) {
    int b = blockIdx.x >> 3, chunk = blockIdx.x & 7;
    int col = (chunk << 8) + threadIdx.x;
    float s = 0.f;
    for (int seg = 0; seg < 64; ++seg)
        s += partial[(size_t)(b * 64 + seg) * H_ + col];
    xp[b * H_ + col] = s * (1.0f / S_);
}

// ---------------------------------------------------------------------------
// big_gemm: fused scorer (split-bf16, fp32-grade) + all-rank projections.
//   y<4 : Hp[kz][M][512] tiles   = xh·swh + xh·swl + xl·swh   (3 MFMA)
//   y>=4: Pp[kz][M][LDP] tiles   = xh·ubh                      (1 MFMA)
// Tile 128x128, BK=32, K-split 2 (kz), 4 waves 2x2, 4x4 frags of 16x16x32.
// LDS rows padded to 40 ushorts -> 2-way max bank aliasing (free).
// ---------------------------------------------------------------------------
__global__ __launch_bounds__(256) void big_gemm(
    const ushort* __restrict__ xhi, const ushort* __restrict__ xlo,
    const ushort* __restrict__ swh, const ushort* __restrict__ swl,
    const ushort* __restrict__ ubh,
    float* __restrict__ Hp, float* __restrict__ Pp) {
    __shared__ ushort Ah[128][40], Al[128][40], Bhs[128][40], Bls[128][40];
    int m0 = blockIdx.x << 7;
    int ny = blockIdx.y;
    int kz = blockIdx.z;
    bool split = ny < 4;
    int tid = threadIdx.x;
    int row = tid >> 1, half = tid & 1;
    int co = half << 4;
    const ushort* ap  = xhi + (size_t)(m0 + row) * H_ + co;
    const ushort* alp = xlo + (size_t)(m0 + row) * H_ + co;
    const ushort* bp; const ushort* blp = alp;  // dummy init
    bool bvalid = true;
    if (split) {
        bp  = swh + (size_t)(ny * 128 + row) * H_ + co;
        blp = swl + (size_t)(ny * 128 + row) * H_ + co;
    } else {
        int br = (ny - 4) * 128 + row;
        bvalid = br < NPROJ;
        bp = ubh + (size_t)(bvalid ? br : 0) * H_ + co;
    }
    int lane = tid & 63, w = tid >> 6;
    int wm = (w >> 1) << 6, wn = (w & 1) << 6;
    int fr = lane & 15, kb = (lane >> 4) << 3;

    f32x4 zero4 = {0.f, 0.f, 0.f, 0.f};
    f32x4 acc[4][4];
#pragma unroll
    for (int i = 0; i < 4; ++i)
#pragma unroll
        for (int j = 0; j < 4; ++j) acc[i][j] = zero4;

    uint4 uz = make_uint4(0, 0, 0, 0);
    int kbeg = kz << 10;
    for (int kt = 0; kt < 32; ++kt) {
        int k0 = kbeg + (kt << 5);
        uint4 a0 = *(const uint4*)(ap + k0);
        uint4 a1 = *(const uint4*)(ap + k0 + 8);
        uint4 b0 = bvalid ? *(const uint4*)(bp + k0) : uz;
        uint4 b1 = bvalid ? *(const uint4*)(bp + k0 + 8) : uz;
        uint4 l0, l1, c0v, c1v;
        if (split) {
            l0  = *(const uint4*)(alp + k0);
            l1  = *(const uint4*)(alp + k0 + 8);
            c0v = *(const uint4*)(blp + k0);
            c1v = *(const uint4*)(blp + k0 + 8);
        }
        __syncthreads();
        *(uint4*)&Ah[row][co]      = a0;
        *(uint4*)&Ah[row][co + 8]  = a1;
        *(uint4*)&Bhs[row][co]     = b0;
        *(uint4*)&Bhs[row][co + 8] = b1;
        if (split) {
            *(uint4*)&Al[row][co]      = l0;
            *(uint4*)&Al[row][co + 8]  = l1;
            *(uint4*)&Bls[row][co]     = c0v;
            *(uint4*)&Bls[row][co + 8] = c1v;
        }
        __syncthreads();
        bf16x8 ah[4], bh[4], al4[4], bl4[4];
#pragma unroll
        for (int mt = 0; mt < 4; ++mt)
            ah[mt] = *(const bf16x8*)&Ah[wm + (mt << 4) + fr][kb];
#pragma unroll
        for (int nt = 0; nt < 4; ++nt)
            bh[nt] = *(const bf16x8*)&Bhs[wn + (nt << 4) + fr][kb];
        if (split) {
#pragma unroll
            for (int mt = 0; mt < 4; ++mt)
                al4[mt] = *(const bf16x8*)&Al[wm + (mt << 4) + fr][kb];
#pragma unroll
            for (int nt = 0; nt < 4; ++nt)
                bl4[nt] = *(const bf16x8*)&Bls[wn + (nt << 4) + fr][kb];
        }
#pragma unroll
        for (int mt = 0; mt < 4; ++mt)
#pragma unroll
            for (int nt = 0; nt < 4; ++nt) {
                acc[mt][nt] = __builtin_amdgcn_mfma_f32_16x16x32_bf16(
                    ah[mt], bh[nt], acc[mt][nt], 0, 0, 0);
                if (split) {
                    acc[mt][nt] = __builtin_amdgcn_mfma_f32_16x16x32_bf16(
                        ah[mt], bl4[nt], acc[mt][nt], 0, 0, 0);
                    acc[mt][nt] = __builtin_amdgcn_mfma_f32_16x16x32_bf16(
                        al4[mt], bh[nt], acc[mt][nt], 0, 0, 0);
                }
            }
    }

    int orr = (lane >> 4) << 2;
    if (split) {
        float* dst = Hp + (size_t)kz * M_ * F_;
#pragma unroll
        for (int mt = 0; mt < 4; ++mt)
#pragma unroll
            for (int r = 0; r < 4; ++r) {
                int m = m0 + wm + (mt << 4) + orr + r;
                float* cr = dst + (size_t)m * F_ + (ny << 7) + wn;
#pragma unroll
                for (int nt = 0; nt < 4; ++nt)
                    cr[(nt << 4) + fr] = acc[mt][nt][r];
            }
    } else {
        float* dst = Pp + (size_t)kz * M_ * LDP;
        int nb0 = (ny - 4) << 7;
#pragma unroll
        for (int mt = 0; mt < 4; ++mt)
#pragma unroll
            for (int r = 0; r < 4; ++r) {
                int m = m0 + wm + (mt << 4) + orr + r;
                float* cr = dst + (size_t)m * LDP;
#pragma unroll
                for (int nt = 0; nt < 4; ++nt) {
                    int c = nb0 + wn + (nt << 4) + fr;
                    if (c < NPROJ) cr[c] = acc[mt][nt][r];
                }
            }
    }
}

// ---------------------------------------------------------------------------
// route_decide: blocks 0..511 do token routing (from Hp partials);
// block 512 does the cache-lookup + rank decision (from xp).
// flags: [0]=n_crit [1]=rank_idx [2]=hit [3]=best
// ---------------------------------------------------------------------------
__global__ __launch_bounds__(256) void route_decide(
    const float* __restrict__ Hp, const float* __restrict__ sb1,
    const float* __restrict__ sw2, const float* __restrict__ sb2,
    const float* __restrict__ pos, const float* __restrict__ xp,
    const float* __restrict__ kpw, const float* __restrict__ ck,
    const float* __restrict__ cw1, const float* __restrict__ cb1,
    const float* __restrict__ cw2, const float* __restrict__ cb2,
    int* __restrict__ flags, int* __restrict__ route, int* __restrict__ clist) {
    __shared__ float xpL[2 * H_];
    __shared__ float qk_s[64], ce_s[128], sims_s[NC_], sc_s[8];
    __shared__ float qn_s;
    int tid = threadIdx.x;
    if (blockIdx.x < 512) {
        int m = (blockIdx.x << 2) + (tid >> 6);
        int lane = tid & 63;
        const float* h0 = Hp + (size_t)m * F_;
        const float* h1 = Hp + (size_t)M_ * F_ + (size_t)m * F_;
        float s = 0.f;
        for (int f = lane; f < F_; f += 64)
            s += fmaxf(h0[f] + h1[f] + sb1[f], 0.f) * sw2[f];
        for (int off = 32; off > 0; off >>= 1) s += __shfl_down(s, off, 64);
        if (lane == 0) {
            float content = s + sb2[0];
            int si = m & (S_ - 1);
            float imp = 1.0f / (1.0f + expf(-(content + 0.1f * pos[si])));
            if (si == 0 || si == S_ - 1) imp *= 2.0f;
            int rt = (imp > 0.8f) ? 0 : ((imp < 0.3f) ? 1 : 2);
            route[m] = rt;
            if (rt == 0) {
                int idx = atomicAdd(&flags[0], 1);
                clist[idx] = m;
            }
        }
        return;
    }
    // ---- decide block ----
    for (int i = tid; i < 2 * H_; i += 256) xpL[i] = xp[i];
    __syncthreads();
    int wv = tid >> 6, lane = tid & 63;
    for (int r = 0; r < 16; ++r) {               // qk: 64 outputs
        int o = (r << 2) + wv;
        int b = o >> 5, d = o & 31;
        const float* wr = kpw + (size_t)d * H_;
        const float* xr = xpL + b * H_;
        float s = 0.f;
        for (int k = lane; k < H_; k += 64) s += xr[k] * wr[k];
        for (int off = 32; off > 0; off >>= 1) s += __shfl_down(s, off, 64);
        if (lane == 0) qk_s[o] = s;
    }
    for (int r = 0; r < 32; ++r) {               // ce: 128 outputs
        int o = (r << 2) + wv;
        int b = o >> 6, j = o & 63;
        const float* wr = cw1 + (size_t)j * H_;
        const float* xr = xpL + b * H_;
        float s = 0.f;
        for (int k = lane; k < H_; k += 64) s += xr[k] * wr[k];
        for (int off = 32; off > 0; off >>= 1) s += __shfl_down(s, off, 64);
        if (lane == 0) ce_s[o] = fmaxf(s + cb1[j], 0.f);
    }
    __syncthreads();
    if (tid == 0) {
        for (int b = 0; b < B_; ++b) {
            float nn = 0.f;
            for (int d = 0; d < KD_; ++d) { float v = qk_s[b * KD_ + d]; nn += v * v; }
            float den = fmaxf(sqrtf(nn), 1e-8f);
            for (int d = 0; d < KD_; ++d) qk_s[b * KD_ + d] /= den;
        }
        float qn = 0.f;
        for (int i = 0; i < B_ * KD_; ++i) qn += qk_s[i] * qk_s[i];
        qn_s = fmaxf(sqrtf(qn), 1e-8f);
    }
    __syncthreads();
    if (tid < NC_) {
        float dot = 0.f, nn = 0.f;
        for (int i = 0; i < B_ * KD_; ++i) {
            float c = ck[tid * (B_ * KD_) + i];
            dot += c * qk_s[i]; nn += c * c;
        }
        sims_s[tid] = dot / (fmaxf(sqrtf(nn), 1e-8f) * qn_s);
    }
    if (tid >= 64 && tid < 72) {
        int p = tid - 64, b = p >> 2, o = p & 3;
        float v = cb2[o];
        for (int j = 0; j < 64; ++j) v += ce_s[b * 64 + j] * cw2[o * 64 + j];
        sc_s[p] = v;
    }
    __syncthreads();
    if (tid == 0) {
        float bestv = -1e30f; int best = 0;
        for (int n = 0; n < NC_; ++n)
            if (sims_s[n] > bestv) { bestv = sims_s[n]; best = n; }
        flags[2] = (bestv >= 0.95f) ? 1 : 0;
        flags[3] = best;
        float bs = -1e30f; int bi = 0;
        for (int p = 0; p < 8; ++p)
            if (sc_s[p] > bs) { bs = sc_s[p]; bi = p; }
        flags[1] = bi & 3;
    }
}

// ---------------------------------------------------------------------------
// crit_gemm: gathered-row bf16 MFMA GEMM, out[row] = x[row]@lw^T + lb
// for the dynamic n_crit rows. Tile 128x128, BK=32, padded LDS.
// ---------------------------------------------------------------------------
__global__ __launch_bounds__(256) void crit_gemm(
    const ushort* __restrict__ xhi, const ushort* __restrict__ lwh,
    const float* __restrict__ lb, const int* __restrict__ clist,
    const int* __restrict__ flags, float* __restrict__ out) {
    __shared__ ushort Ah[128][40], Bh[128][40];
    int M = flags[0];
    int m0 = blockIdx.x << 7;
    if (m0 >= M) return;
    int n0 = blockIdx.y << 7;
    int tid = threadIdx.x;
    int row = tid >> 1, half = tid & 1, co = half << 4;
    int gm = m0 + row;
    int arow = clist[gm < M ? gm : (M - 1)];
    const ushort* ap = xhi + (size_t)arow * H_ + co;
    const ushort* bp = lwh + (size_t)(n0 + row) * H_ + co;

    int lane = tid & 63, w = tid >> 6;
    int wm = (w >> 1) << 6, wn = (w & 1) << 6;
    int fr = lane & 15, kb = (lane >> 4) << 3;

    f32x4 zero4 = {0.f, 0.f, 0.f, 0.f};
    f32x4 acc[4][4];
#pragma unroll
    for (int i = 0; i < 4; ++i)
#pragma unroll
        for (int j = 0; j < 4; ++j) acc[i][j] = zero4;

    for (int kt = 0; kt < 64; ++kt) {
        int k0 = kt << 5;
        uint4 a0 = *(const uint4*)(ap + k0);
        uint4 a1 = *(const uint4*)(ap + k0 + 8);
        uint4 b0 = *(const uint4*)(bp + k0);
        uint4 b1 = *(const uint4*)(bp + k0 + 8);
        __syncthreads();
        *(uint4*)&Ah[row][co]     = a0;
        *(uint4*)&Ah[row][co + 8] = a1;
        *(uint4*)&Bh[row][co]     = b0;
        *(uint4*)&Bh[row][co + 8] = b1;
        __syncthreads();
        bf16x8 af[4], bf[4];
#pragma unroll
        for (int mt = 0; mt < 4; ++mt)
            af[mt] = *(const bf16x8*)&Ah[wm + (mt << 4) + fr][kb];
#pragma unroll
        for (int nt = 0; nt < 4; ++nt)
            bf[nt] = *(const bf16x8*)&Bh[wn + (nt << 4) + fr][kb];
#pragma unroll
        for (int mt = 0; mt < 4; ++mt)
#pragma unroll
            for (int nt = 0; nt < 4; ++nt)
                acc[mt][nt] = __builtin_amdgcn_mfma_f32_16x16x32_bf16(
                    af[mt], bf[nt], acc[mt][nt], 0, 0, 0);
    }

    int orr = (lane >> 4) << 2;
#pragma unroll
    for (int mt = 0; mt < 4; ++mt)
#pragma unroll
        for (int r = 0; r < 4; ++r) {
            int m = m0 + wm + (mt << 4) + orr + r;
            if (m < M) {
                float* cr = out + (size_t)clist[m] * H_;
#pragma unroll
                for (int nt = 0; nt < 4; ++nt) {
                    int c = n0 + wn + (nt << 4) + fr;
                    cr[c] = acc[mt][nt][r] + lb[c];
                }
            }
        }
}

// ---------------------------------------------------------------------------
// stage2: low-rank apply + routing epilogue per class (reads Pp partials).
// cls==1 (simple): out = x + (hit ? cache_delta[best] : t4 @ v4^T)
// cls==2 (normal): out = x + tr @ v_rank^T
// ---------------------------------------------------------------------------
__global__ __launch_bounds__(256) void stage2_kernel(
    int cls, const float* __restrict__ x, const float* __restrict__ Pp,
    const float* __restrict__ v4, const float* __restrict__ v12,
    const float* __restrict__ v40, const float* __restrict__ v128,
    const float* __restrict__ cd, const int* __restrict__ flags,
    const int* __restrict__ route, float* __restrict__ out) {
    __shared__ float Ts[16][132];
    __shared__ int act[16];
    int tid = threadIdx.x;
    int m0 = blockIdx.x << 4;

    const float* V; int Kr; int off;
    if (cls == 1) { V = v4; Kr = 4; off = 0; }
    else {
        int r = flags[1];
        V   = (r == 0) ? v4 : (r == 1) ? v12 : (r == 2) ? v40 : v128;
        Kr  = (r == 0) ? 4  : (r == 1) ? 12  : (r == 2) ? 40  : 128;
        off = (r == 0) ? 0  : (r == 1) ? 4   : (r == 2) ? 16  : 56;
    }
    int hit = flags[2], best = flags[3];

    if (tid < 16) act[tid] = (route[m0 + tid] == cls) ? 1 : 0;
    const float* Pp1 = Pp + (size_t)M_ * LDP;
    for (int idx = tid; idx < 16 * Kr; idx += 256) {
        int i = idx / Kr, j = idx - i * Kr;
        size_t o = (size_t)(m0 + i) * LDP + off + j;
        Ts[i][j] = Pp[o] + Pp1[o];
    }
    __syncthreads();
    bool some = false;
#pragma unroll
    for (int i = 0; i < 16; ++i) some |= (act[i] != 0);
    if (!some) return;

    bool use_delta = (cls == 1) && hit;
    for (int c = tid; c < H_; c += 256) {
        float acc[16];
#pragma unroll
        for (int i = 0; i < 16; ++i) acc[i] = 0.f;
        if (!use_delta) {
            const float* vrow = V + (size_t)c * Kr;
            for (int j = 0; j < Kr; j += 4) {
                const float4 vv = *(const float4*)(vrow + j);
#pragma unroll
                for (int i = 0; i < 16; ++i) {
                    const float4 tv = *(const float4*)&Ts[i][j];
                    acc[i] += tv.x * vv.x + tv.y * vv.y + tv.z * vv.z + tv.w * vv.w;
                }
            }
        }
#pragma unroll
        for (int i = 0; i < 16; ++i) {
            if (act[i]) {
                size_t o = (size_t)(m0 + i) * H_ + c;
                float upd = use_delta
                    ? cd[(size_t)best * (size_t)(M_ * H_) + o]
                    : acc[i];
                out[o] = x[o] + upd;
            }
        }
    }
}

// ---------------------------------------------------------------------------
extern "C" void kernel_launch(void* const* d_in, const int* in_sizes, int n_in,
                              void* d_out, int out_size, void* d_ws, size_t ws_size,
                              hipStream_t stream) {
    const float* x    = (const float*)d_in[0];
    const float* sw1  = (const float*)d_in[1];
    const float* sb1  = (const float*)d_in[2];
    const float* sw2  = (const float*)d_in[3];
    const float* sb2  = (const float*)d_in[4];
    const float* pos  = (const float*)d_in[5];
    const float* kpw  = (const float*)d_in[6];
    const float* ck   = (const float*)d_in[7];
    const float* cd   = (const float*)d_in[8];
    const float* cw1  = (const float*)d_in[9];
    const float* cb1  = (const float*)d_in[10];
    const float* cw2  = (const float*)d_in[11];
    const float* cb2  = (const float*)d_in[12];
    const float* u4   = (const float*)d_in[13];
    const float* v4   = (const float*)d_in[14];
    const float* u12  = (const float*)d_in[15];
    const float* v12  = (const float*)d_in[16];
    const float* u40  = (const float*)d_in[17];
    const float* v40  = (const float*)d_in[18];
    const float* u128 = (const float*)d_in[19];
    const float* v128 = (const float*)d_in[20];
    const float* lw   = (const float*)d_in[21];
    const float* lb   = (const float*)d_in[22];
    float* out = (float*)d_out;

    // ---- workspace layout (~34 MB) ----
    ushort* xhi = (ushort*)d_ws;                       // [M,H]
    ushort* xlo = xhi + (size_t)M_ * H_;               // [M,H]
    ushort* lwh = xlo + (size_t)M_ * H_;               // [H,H]
    ushort* swh = lwh + (size_t)H_ * H_;               // [F,H]
    ushort* swl = swh + (size_t)F_ * H_;               // [F,H]
    ushort* ubh = swl + (size_t)F_ * H_;               // [NPROJ,H]
    float* fbase   = (float*)(ubh + (size_t)NPROJ * H_);
    float* xp      = fbase;                            // [2,H]
    float* partial = xp + 2 * H_;                      // [128,H]
    float* Pp      = partial + 128 * H_;               // [2,M,LDP]
    int*   flags   = (int*)(Pp + 2 * (size_t)M_ * LDP);
    int*   route   = flags + 8;                        // [M]
    int*   clist   = route + M_;                       // [M]
    // Hp [2][M][F] aliases d_out's first 8.39 MB: consumed by route_decide
    // before any out row is written; every out element is then written by
    // exactly one of {crit_gemm, stage2 cls1, stage2 cls2}.
    float* Hp = out;

    hipMemsetAsync(flags, 0, sizeof(int), stream);   // n_crit = 0

    conv_kernel<<<1500, 256, 0, stream>>>(x, lw, sw1, u4, u12, u40, u128,
                                          xhi, xlo, lwh, swh, swl, ubh, partial);
    pool_final_kernel<<<16, 256, 0, stream>>>(partial, xp);
    big_gemm<<<dim3(16, 6, 2), 256, 0, stream>>>(xhi, xlo, swh, swl, ubh, Hp, Pp);
    route_decide<<<513, 256, 0, stream>>>(Hp, sb1, sw2, sb2, pos, xp, kpw, ck,
                                          cw1, cb1, cw2, cb2, flags, route, clist);
    crit_gemm<<<dim3(16, 16), 256, 0, stream>>>(xhi, lwh, lb, clist, flags, out);
    stage2_kernel<<<128, 256, 0, stream>>>(1, x, Pp, v4, v12, v40, v128,
                                           cd, flags, route, out);
    stage2_kernel<<<128, 256, 0, stream>>>(2, x, Pp, v4, v12, v40, v128,
                                           cd, flags, route, out);
}

// Round 4
// 607.845 us; speedup vs baseline: 1.6849x; 1.6849x over previous
//
#include <hip/hip_runtime.h>
#include <math.h>

#define B_  2
#define S_  1024
#define H_  2048
#define F_  512          // H/4
#define KD_ 32
#define NC_ 16
#define M_  2048         // B*S tokens
#define NPROJ 184        // 4+12+40+128 packed u-rows
#define LDP 192          // proj row stride

typedef __attribute__((ext_vector_type(8))) short bf16x8;
typedef __attribute__((ext_vector_type(4))) float f32x4;

__device__ __forceinline__ ushort f2bf(float f) {
    unsigned u = __float_as_uint(f);
    u += 0x7FFFu + ((u >> 16) & 1u);   // RNE
    return (ushort)(u >> 16);
}
__device__ __forceinline__ float bf2f(ushort h) {
    return __uint_as_float(((unsigned)h) << 16);
}
__device__ __forceinline__ uint4 pack_hi8(float4 a, float4 b) {
    uint4 r;
    r.x = (unsigned)f2bf(a.x) | ((unsigned)f2bf(a.y) << 16);
    r.y = (unsigned)f2bf(a.z) | ((unsigned)f2bf(a.w) << 16);
    r.z = (unsigned)f2bf(b.x) | ((unsigned)f2bf(b.y) << 16);
    r.w = (unsigned)f2bf(b.z) | ((unsigned)f2bf(b.w) << 16);
    return r;
}
__device__ __forceinline__ void pack_hilo8(float4 a, float4 b, uint4* hi, uint4* lo) {
    float v[8] = {a.x, a.y, a.z, a.w, b.x, b.y, b.z, b.w};
    unsigned h[8], l[8];
#pragma unroll
    for (int i = 0; i < 8; ++i) {
        ushort hh = f2bf(v[i]);
        h[i] = hh;
        l[i] = f2bf(v[i] - bf2f(hh));
    }
    *hi = make_uint4(h[0] | (h[1] << 16), h[2] | (h[3] << 16),
                     h[4] | (h[5] << 16), h[6] | (h[7] << 16));
    *lo = make_uint4(l[0] | (l[1] << 16), l[2] | (l[3] << 16),
                     l[4] | (l[5] << 16), l[6] | (l[7] << 16));
}

// ---------------------------------------------------------------------------
// conv_kernel: bf16 conversions + pool partials, one pass.
// blocks 0..127    : x rows blk*16..+16 -> xhi,xlo + column-sum partial[blk]
// blocks 128..1151 : lw (flat, hi only)
// blocks 1152..1407: sw1 (flat, hi+lo)
// blocks 1408..1499: u4|u12|u40|u128 -> packed ubh rows {0,4,16,56}
// ---------------------------------------------------------------------------
__global__ __launch_bounds__(256) void conv_kernel(
    const float* __restrict__ x, const float* __restrict__ lw,
    const float* __restrict__ sw1,
    const float* __restrict__ u4, const float* __restrict__ u12,
    const float* __restrict__ u40, const float* __restrict__ u128,
    ushort* __restrict__ xhi, ushort* __restrict__ xlo,
    ushort* __restrict__ lwh, ushort* __restrict__ swh,
    ushort* __restrict__ swl, ushort* __restrict__ ubh,
    float* __restrict__ partial) {
    int blk = blockIdx.x, tid = threadIdx.x;
    if (blk < 128) {
        int c0 = tid << 3;
        float cs0 = 0.f, cs1 = 0.f, cs2 = 0.f, cs3 = 0.f;
        float cs4 = 0.f, cs5 = 0.f, cs6 = 0.f, cs7 = 0.f;
        for (int r = 0; r < 16; ++r) {
            size_t off = (size_t)(blk * 16 + r) * H_ + c0;
            float4 a = *(const float4*)(x + off);
            float4 b = *(const float4*)(x + off + 4);
            cs0 += a.x; cs1 += a.y; cs2 += a.z; cs3 += a.w;
            cs4 += b.x; cs5 += b.y; cs6 += b.z; cs7 += b.w;
            uint4 hi, lo;
            pack_hilo8(a, b, &hi, &lo);
            *(uint4*)(xhi + off) = hi;
            *(uint4*)(xlo + off) = lo;
        }
        float* pr = partial + (size_t)blk * H_ + c0;
        pr[0] = cs0; pr[1] = cs1; pr[2] = cs2; pr[3] = cs3;
        pr[4] = cs4; pr[5] = cs5; pr[6] = cs6; pr[7] = cs7;
    } else if (blk < 1152) {
        size_t base = (size_t)(blk - 128) * 4096 + (size_t)tid * 16;
#pragma unroll
        for (int q = 0; q < 2; ++q) {
            size_t o = base + q * 8;
            float4 a = *(const float4*)(lw + o);
            float4 b = *(const float4*)(lw + o + 4);
            *(uint4*)(lwh + o) = pack_hi8(a, b);
        }
    } else if (blk < 1408) {
        size_t base = (size_t)(blk - 1152) * 4096 + (size_t)tid * 16;
#pragma unroll
        for (int q = 0; q < 2; ++q) {
            size_t o = base + q * 8;
            float4 a = *(const float4*)(sw1 + o);
            float4 b = *(const float4*)(sw1 + o + 4);
            uint4 hi, lo;
            pack_hilo8(a, b, &hi, &lo);
            *(uint4*)(swh + o) = hi;
            *(uint4*)(swl + o) = lo;
        }
    } else {
        const float* src; ushort* dst; int rel;
        if (blk < 1410)      { src = u4;   dst = ubh;            rel = blk - 1408; }
        else if (blk < 1416) { src = u12;  dst = ubh + 4 * H_;   rel = blk - 1410; }
        else if (blk < 1436) { src = u40;  dst = ubh + 16 * H_;  rel = blk - 1416; }
        else                 { src = u128; dst = ubh + 56 * H_;  rel = blk - 1436; }
        size_t base = (size_t)rel * 4096 + (size_t)tid * 16;
#pragma unroll
        for (int q = 0; q < 2; ++q) {
            size_t o = base + q * 8;
            float4 a = *(const float4*)(src + o);
            float4 b = *(const float4*)(src + o + 4);
            *(uint4*)(dst + o) = pack_hi8(a, b);
        }
    }
}

// ---------------------------------------------------------------------------
// pool_final: xp[b][col] = mean over S of x  (from 64 partials per b).
// ---------------------------------------------------------------------------
__global__ __launch_bounds__(256) void pool_final_kernel(
    const float* __restrict__ partial, float* __restrict__ xp) {
    int b = blockIdx.x >> 3, chunk = blockIdx.x & 7;
    int col = (chunk << 8) + threadIdx.x;
    float s = 0.f;
    for (int seg = 0; seg < 64; ++seg)
        s += partial[(size_t)(b * 64 + seg) * H_ + col];
    xp[b * H_ + col] = s * (1.0f / S_);
}

// ---------------------------------------------------------------------------
// decide_dots: 192 blocks, one dot-product output each (parallel, latency-
// hidden). o<64: qk[o] = xp[b]·kpw[d].  o>=64: cedot[o-64] = xp[b]·cw1[j].
// ---------------------------------------------------------------------------
__global__ __launch_bounds__(256) void decide_dots(
    const float* __restrict__ xp, const float* __restrict__ kpw,
    const float* __restrict__ cw1, float* __restrict__ dots) {
    __shared__ float red[4];
    int o = blockIdx.x, tid = threadIdx.x;
    const float* xr;
    const float* wr;
    if (o < 64) {
        xr = xp + (o >> 5) * H_;
        wr = kpw + (size_t)(o & 31) * H_;
    } else {
        int o2 = o - 64;
        xr = xp + (o2 >> 6) * H_;
        wr = cw1 + (size_t)(o2 & 63) * H_;
    }
    int k0 = tid << 3;
    float4 xa = *(const float4*)(xr + k0);
    float4 xb = *(const float4*)(xr + k0 + 4);
    float4 wa = *(const float4*)(wr + k0);
    float4 wb = *(const float4*)(wr + k0 + 4);
    float s = xa.x * wa.x + xa.y * wa.y + xa.z * wa.z + xa.w * wa.w
            + xb.x * wb.x + xb.y * wb.y + xb.z * wb.z + xb.w * wb.w;
    for (int off = 32; off > 0; off >>= 1) s += __shfl_down(s, off, 64);
    if ((tid & 63) == 0) red[tid >> 6] = s;
    __syncthreads();
    if (tid == 0) dots[o] = red[0] + red[1] + red[2] + red[3];
}

// ---------------------------------------------------------------------------
// decide_final: tiny serial tail (O(4K) FLOP), one block.
// flags: [0]=n_crit (memset) [1]=rank_idx [2]=hit [3]=best
// ---------------------------------------------------------------------------
__global__ __launch_bounds__(64) void decide_final(
    const float* __restrict__ dots, const float* __restrict__ ck,
    const float* __restrict__ cb1, const float* __restrict__ cw2,
    const float* __restrict__ cb2, int* __restrict__ flags) {
    __shared__ float qk_s[64], ce_s[128], sims_s[NC_], sc_s[8];
    __shared__ float qn_s;
    int tid = threadIdx.x;
    if (tid < 64) qk_s[tid] = dots[tid];
    if (tid < 64) {
        ce_s[tid]      = fmaxf(dots[64 + tid] + cb1[tid & 63], 0.f);
        ce_s[tid + 64] = fmaxf(dots[128 + tid] + cb1[tid & 63], 0.f);
    }
    __syncthreads();
    if (tid == 0) {
        for (int b = 0; b < B_; ++b) {
            float nn = 0.f;
            for (int d = 0; d < KD_; ++d) { float v = qk_s[b * KD_ + d]; nn += v * v; }
            float den = fmaxf(sqrtf(nn), 1e-8f);
            for (int d = 0; d < KD_; ++d) qk_s[b * KD_ + d] /= den;
        }
        float qn = 0.f;
        for (int i = 0; i < B_ * KD_; ++i) qn += qk_s[i] * qk_s[i];
        qn_s = fmaxf(sqrtf(qn), 1e-8f);
    }
    __syncthreads();
    if (tid < NC_) {
        float dot = 0.f, nn = 0.f;
        for (int i = 0; i < B_ * KD_; ++i) {
            float c = ck[tid * (B_ * KD_) + i];
            dot += c * qk_s[i]; nn += c * c;
        }
        sims_s[tid] = dot / (fmaxf(sqrtf(nn), 1e-8f) * qn_s);
    }
    if (tid >= 32 && tid < 40) {
        int p = tid - 32, b = p >> 2, o = p & 3;
        float v = cb2[o];
        for (int j = 0; j < 64; ++j) v += ce_s[b * 64 + j] * cw2[o * 64 + j];
        sc_s[p] = v;
    }
    __syncthreads();
    if (tid == 0) {
        float bestv = -1e30f; int best = 0;
        for (int n = 0; n < NC_; ++n)
            if (sims_s[n] > bestv) { bestv = sims_s[n]; best = n; }
        flags[2] = (bestv >= 0.95f) ? 1 : 0;
        flags[3] = best;
        float bs = -1e30f; int bi = 0;
        for (int p = 0; p < 8; ++p)
            if (sc_s[p] > bs) { bs = sc_s[p]; bi = p; }
        flags[1] = bi & 3;
    }
}

// ---------------------------------------------------------------------------
// big_gemm: fused scorer (split-bf16, fp32-grade) + all-rank projections.
//   y<4 : Hp[kz][M][512] tiles = xh·swh + xh·swl + xl·swh   (3 MFMA)
//   y>=4: Pp[kz][M][LDP] tiles = xh·ubh                      (1 MFMA)
// Tile 128x128, BK=32, K-split 2 (kz), 4 waves 2x2, 4x4 frags of 16x16x32.
// ---------------------------------------------------------------------------
__global__ __launch_bounds__(256) void big_gemm(
    const ushort* __restrict__ xhi, const ushort* __restrict__ xlo,
    const ushort* __restrict__ swh, const ushort* __restrict__ swl,
    const ushort* __restrict__ ubh,
    float* __restrict__ Hp, float* __restrict__ Pp) {
    __shared__ ushort Ah[128][40], Al[128][40], Bhs[128][40], Bls[128][40];
    int m0 = blockIdx.x << 7;
    int ny = blockIdx.y;
    int kz = blockIdx.z;
    bool split = ny < 4;
    int tid = threadIdx.x;
    int row = tid >> 1, half = tid & 1;
    int co = half << 4;
    const ushort* ap  = xhi + (size_t)(m0 + row) * H_ + co;
    const ushort* alp = xlo + (size_t)(m0 + row) * H_ + co;
    const ushort* bp; const ushort* blp = alp;
    bool bvalid = true;
    if (split) {
        bp  = swh + (size_t)(ny * 128 + row) * H_ + co;
        blp = swl + (size_t)(ny * 128 + row) * H_ + co;
    } else {
        int br = (ny - 4) * 128 + row;
        bvalid = br < NPROJ;
        bp = ubh + (size_t)(bvalid ? br : 0) * H_ + co;
    }
    int lane = tid & 63, w = tid >> 6;
    int wm = (w >> 1) << 6, wn = (w & 1) << 6;
    int fr = lane & 15, kb = (lane >> 4) << 3;

    f32x4 zero4 = {0.f, 0.f, 0.f, 0.f};
    f32x4 acc[4][4];
#pragma unroll
    for (int i = 0; i < 4; ++i)
#pragma unroll
        for (int j = 0; j < 4; ++j) acc[i][j] = zero4;

    uint4 uz = make_uint4(0, 0, 0, 0);
    int kbeg = kz << 10;
    for (int kt = 0; kt < 32; ++kt) {
        int k0 = kbeg + (kt << 5);
        uint4 a0 = *(const uint4*)(ap + k0);
        uint4 a1 = *(const uint4*)(ap + k0 + 8);
        uint4 b0 = bvalid ? *(const uint4*)(bp + k0) : uz;
        uint4 b1 = bvalid ? *(const uint4*)(bp + k0 + 8) : uz;
        uint4 l0, l1, c0v, c1v;
        if (split) {
            l0  = *(const uint4*)(alp + k0);
            l1  = *(const uint4*)(alp + k0 + 8);
            c0v = *(const uint4*)(blp + k0);
            c1v = *(const uint4*)(blp + k0 + 8);
        }
        __syncthreads();
        *(uint4*)&Ah[row][co]      = a0;
        *(uint4*)&Ah[row][co + 8]  = a1;
        *(uint4*)&Bhs[row][co]     = b0;
        *(uint4*)&Bhs[row][co + 8] = b1;
        if (split) {
            *(uint4*)&Al[row][co]      = l0;
            *(uint4*)&Al[row][co + 8]  = l1;
            *(uint4*)&Bls[row][co]     = c0v;
            *(uint4*)&Bls[row][co + 8] = c1v;
        }
        __syncthreads();
        bf16x8 ah[4], bh[4], al4[4], bl4[4];
#pragma unroll
        for (int mt = 0; mt < 4; ++mt)
            ah[mt] = *(const bf16x8*)&Ah[wm + (mt << 4) + fr][kb];
#pragma unroll
        for (int nt = 0; nt < 4; ++nt)
            bh[nt] = *(const bf16x8*)&Bhs[wn + (nt << 4) + fr][kb];
        if (split) {
#pragma unroll
            for (int mt = 0; mt < 4; ++mt)
                al4[mt] = *(const bf16x8*)&Al[wm + (mt << 4) + fr][kb];
#pragma unroll
            for (int nt = 0; nt < 4; ++nt)
                bl4[nt] = *(const bf16x8*)&Bls[wn + (nt << 4) + fr][kb];
        }
#pragma unroll
        for (int mt = 0; mt < 4; ++mt)
#pragma unroll
            for (int nt = 0; nt < 4; ++nt) {
                acc[mt][nt] = __builtin_amdgcn_mfma_f32_16x16x32_bf16(
                    ah[mt], bh[nt], acc[mt][nt], 0, 0, 0);
                if (split) {
                    acc[mt][nt] = __builtin_amdgcn_mfma_f32_16x16x32_bf16(
                        ah[mt], bl4[nt], acc[mt][nt], 0, 0, 0);
                    acc[mt][nt] = __builtin_amdgcn_mfma_f32_16x16x32_bf16(
                        al4[mt], bh[nt], acc[mt][nt], 0, 0, 0);
                }
            }
    }

    int orr = (lane >> 4) << 2;
    if (split) {
        float* dst = Hp + (size_t)kz * M_ * F_;
#pragma unroll
        for (int mt = 0; mt < 4; ++mt)
#pragma unroll
            for (int r = 0; r < 4; ++r) {
                int m = m0 + wm + (mt << 4) + orr + r;
                float* cr = dst + (size_t)m * F_ + (ny << 7) + wn;
#pragma unroll
                for (int nt = 0; nt < 4; ++nt)
                    cr[(nt << 4) + fr] = acc[mt][nt][r];
            }
    } else {
        float* dst = Pp + (size_t)kz * M_ * LDP;
        int nb0 = (ny - 4) << 7;
#pragma unroll
        for (int mt = 0; mt < 4; ++mt)
#pragma unroll
            for (int r = 0; r < 4; ++r) {
                int m = m0 + wm + (mt << 4) + orr + r;
                float* cr = dst + (size_t)m * LDP;
#pragma unroll
                for (int nt = 0; nt < 4; ++nt) {
                    int c = nb0 + wn + (nt << 4) + fr;
                    if (c < NPROJ) cr[c] = acc[mt][nt][r];
                }
            }
    }
}

// ---------------------------------------------------------------------------
// route_kernel: token routing from Hp partials. 512 blocks, 1 wave/token.
// ---------------------------------------------------------------------------
__global__ __launch_bounds__(256) void route_kernel(
    const float* __restrict__ Hp, const float* __restrict__ sb1,
    const float* __restrict__ sw2, const float* __restrict__ sb2,
    const float* __restrict__ pos,
    int* __restrict__ flags, int* __restrict__ route, int* __restrict__ clist) {
    int tid = threadIdx.x;
    int m = (blockIdx.x << 2) + (tid >> 6);
    int lane = tid & 63;
    const float* h0 = Hp + (size_t)m * F_;
    const float* h1 = Hp + (size_t)M_ * F_ + (size_t)m * F_;
    float s = 0.f;
    for (int f = lane; f < F_; f += 64)
        s += fmaxf(h0[f] + h1[f] + sb1[f], 0.f) * sw2[f];
    for (int off = 32; off > 0; off >>= 1) s += __shfl_down(s, off, 64);
    if (lane == 0) {
        float content = s + sb2[0];
        int si = m & (S_ - 1);
        float imp = 1.0f / (1.0f + expf(-(content + 0.1f * pos[si])));
        if (si == 0 || si == S_ - 1) imp *= 2.0f;
        int rt = (imp > 0.8f) ? 0 : ((imp < 0.3f) ? 1 : 2);
        route[m] = rt;
        if (rt == 0) {
            int idx = atomicAdd(&flags[0], 1);
            clist[idx] = m;
        }
    }
}

// ---------------------------------------------------------------------------
// crit_gemm: gathered-row bf16 MFMA GEMM, out[row] = x[row]@lw^T + lb.
// ---------------------------------------------------------------------------
__global__ __launch_bounds__(256) void crit_gemm(
    const ushort* __restrict__ xhi, const ushort* __restrict__ lwh,
    const float* __restrict__ lb, const int* __restrict__ clist,
    const int* __restrict__ flags, float* __restrict__ out) {
    __shared__ ushort Ah[128][40], Bh[128][40];
    int M = flags[0];
    int m0 = blockIdx.x << 7;
    if (m0 >= M) return;
    int n0 = blockIdx.y << 7;
    int tid = threadIdx.x;
    int row = tid >> 1, half = tid & 1, co = half << 4;
    int gm = m0 + row;
    int arow = clist[gm < M ? gm : (M - 1)];
    const ushort* ap = xhi + (size_t)arow * H_ + co;
    const ushort* bp = lwh + (size_t)(n0 + row) * H_ + co;

    int lane = tid & 63, w = tid >> 6;
    int wm = (w >> 1) << 6, wn = (w & 1) << 6;
    int fr = lane & 15, kb = (lane >> 4) << 3;

    f32x4 zero4 = {0.f, 0.f, 0.f, 0.f};
    f32x4 acc[4][4];
#pragma unroll
    for (int i = 0; i < 4; ++i)
#pragma unroll
        for (int j = 0; j < 4; ++j) acc[i][j] = zero4;

    for (int kt = 0; kt < 64; ++kt) {
        int k0 = kt << 5;
        uint4 a0 = *(const uint4*)(ap + k0);
        uint4 a1 = *(const uint4*)(ap + k0 + 8);
        uint4 b0 = *(const uint4*)(bp + k0);
        uint4 b1 = *(const uint4*)(bp + k0 + 8);
        __syncthreads();
        *(uint4*)&Ah[row][co]     = a0;
        *(uint4*)&Ah[row][co + 8] = a1;
        *(uint4*)&Bh[row][co]     = b0;
        *(uint4*)&Bh[row][co + 8] = b1;
        __syncthreads();
        bf16x8 af[4], bf[4];
#pragma unroll
        for (int mt = 0; mt < 4; ++mt)
            af[mt] = *(const bf16x8*)&Ah[wm + (mt << 4) + fr][kb];
#pragma unroll
        for (int nt = 0; nt < 4; ++nt)
            bf[nt] = *(const bf16x8*)&Bh[wn + (nt << 4) + fr][kb];
#pragma unroll
        for (int mt = 0; mt < 4; ++mt)
#pragma unroll
            for (int nt = 0; nt < 4; ++nt)
                acc[mt][nt] = __builtin_amdgcn_mfma_f32_16x16x32_bf16(
                    af[mt], bf[nt], acc[mt][nt], 0, 0, 0);
    }

    int orr = (lane >> 4) << 2;
#pragma unroll
    for (int mt = 0; mt < 4; ++mt)
#pragma unroll
        for (int r = 0; r < 4; ++r) {
            int m = m0 + wm + (mt << 4) + orr + r;
            if (m < M) {
                float* cr = out + (size_t)clist[m] * H_;
#pragma unroll
                for (int nt = 0; nt < 4; ++nt) {
                    int c = n0 + wn + (nt << 4) + fr;
                    cr[c] = acc[mt][nt][r] + lb[c];
                }
            }
        }
}

// ---------------------------------------------------------------------------
// stage2: low-rank apply + routing epilogue per class (reads Pp partials).
// cls==1 (simple): out = x + (hit ? cache_delta[best] : t4 @ v4^T)
// cls==2 (normal): out = x + tr @ v_rank^T
// ---------------------------------------------------------------------------
__global__ __launch_bounds__(256) void stage2_kernel(
    int cls, const float* __restrict__ x, const float* __restrict__ Pp,
    const float* __restrict__ v4, const float* __restrict__ v12,
    const float* __restrict__ v40, const float* __restrict__ v128,
    const float* __restrict__ cd, const int* __restrict__ flags,
    const int* __restrict__ route, float* __restrict__ out) {
    __shared__ float Ts[16][132];
    __shared__ int act[16];
    int tid = threadIdx.x;
    int m0 = blockIdx.x << 4;

    const float* V; int Kr; int off;
    if (cls == 1) { V = v4; Kr = 4; off = 0; }
    else {
        int r = flags[1];
        V   = (r == 0) ? v4 : (r == 1) ? v12 : (r == 2) ? v40 : v128;
        Kr  = (r == 0) ? 4  : (r == 1) ? 12  : (r == 2) ? 40  : 128;
        off = (r == 0) ? 0  : (r == 1) ? 4   : (r == 2) ? 16  : 56;
    }
    int hit = flags[2], best = flags[3];

    if (tid < 16) act[tid] = (route[m0 + tid] == cls) ? 1 : 0;
    const float* Pp1 = Pp + (size_t)M_ * LDP;
    for (int idx = tid; idx < 16 * Kr; idx += 256) {
        int i = idx / Kr, j = idx - i * Kr;
        size_t o = (size_t)(m0 + i) * LDP + off + j;
        Ts[i][j] = Pp[o] + Pp1[o];
    }
    __syncthreads();
    bool some = false;
#pragma unroll
    for (int i = 0; i < 16; ++i) some |= (act[i] != 0);
    if (!some) return;

    bool use_delta = (cls == 1) && hit;
    for (int c = tid; c < H_; c += 256) {
        float acc[16];
#pragma unroll
        for (int i = 0; i < 16; ++i) acc[i] = 0.f;
        if (!use_delta) {
            const float* vrow = V + (size_t)c * Kr;
            for (int j = 0; j < Kr; j += 4) {
                const float4 vv = *(const float4*)(vrow + j);
#pragma unroll
                for (int i = 0; i < 16; ++i) {
                    const float4 tv = *(const float4*)&Ts[i][j];
                    acc[i] += tv.x * vv.x + tv.y * vv.y + tv.z * vv.z + tv.w * vv.w;
                }
            }
        }
#pragma unroll
        for (int i = 0; i < 16; ++i) {
            if (act[i]) {
                size_t o = (size_t)(m0 + i) * H_ + c;
                float upd = use_delta
                    ? cd[(size_t)best * (size_t)(M_ * H_) + o]
                    : acc[i];
                out[o] = x[o] + upd;
            }
        }
    }
}

// ---------------------------------------------------------------------------
extern "C" void kernel_launch(void* const* d_in, const int* in_sizes, int n_in,
                              void* d_out, int out_size, void* d_ws, size_t ws_size,
                              hipStream_t stream) {
    const float* x    = (const float*)d_in[0];
    const float* sw1  = (const float*)d_in[1];
    const float* sb1  = (const float*)d_in[2];
    const float* sw2  = (const float*)d_in[3];
    const float* sb2  = (const float*)d_in[4];
    const float* pos  = (const float*)d_in[5];
    const float* kpw  = (const float*)d_in[6];
    const float* ck   = (const float*)d_in[7];
    const float* cd   = (const float*)d_in[8];
    const float* cw1  = (const float*)d_in[9];
    const float* cb1  = (const float*)d_in[10];
    const float* cw2  = (const float*)d_in[11];
    const float* cb2  = (const float*)d_in[12];
    const float* u4   = (const float*)d_in[13];
    const float* v4   = (const float*)d_in[14];
    const float* u12  = (const float*)d_in[15];
    const float* v12  = (const float*)d_in[16];
    const float* u40  = (const float*)d_in[17];
    const float* v40  = (const float*)d_in[18];
    const float* u128 = (const float*)d_in[19];
    const float* v128 = (const float*)d_in[20];
    const float* lw   = (const float*)d_in[21];
    const float* lb   = (const float*)d_in[22];
    float* out = (float*)d_out;

    // ---- workspace layout (~34 MB) ----
    ushort* xhi = (ushort*)d_ws;                       // [M,H]
    ushort* xlo = xhi + (size_t)M_ * H_;               // [M,H]
    ushort* lwh = xlo + (size_t)M_ * H_;               // [H,H]
    ushort* swh = lwh + (size_t)H_ * H_;               // [F,H]
    ushort* swl = swh + (size_t)F_ * H_;               // [F,H]
    ushort* ubh = swl + (size_t)F_ * H_;               // [NPROJ,H]
    float* fbase   = (float*)(ubh + (size_t)NPROJ * H_);
    float* xp      = fbase;                            // [2,H]
    float* partial = xp + 2 * H_;                      // [128,H]
    float* Pp      = partial + 128 * H_;               // [2,M,LDP]
    float* dots    = Pp + 2 * (size_t)M_ * LDP;        // [192]
    int*   flags   = (int*)(dots + 256);
    int*   route   = flags + 8;                        // [M]
    int*   clist   = route + M_;                       // [M]
    // Hp [2][M][F] aliases d_out's first 8.39 MB: consumed by route_kernel
    // before any out row is written; every out element is then written by
    // exactly one of {crit_gemm, stage2 cls1, stage2 cls2}.
    float* Hp = out;

    hipMemsetAsync(flags, 0, sizeof(int), stream);   // n_crit = 0

    conv_kernel<<<1500, 256, 0, stream>>>(x, lw, sw1, u4, u12, u40, u128,
                                          xhi, xlo, lwh, swh, swl, ubh, partial);
    pool_final_kernel<<<16, 256, 0, stream>>>(partial, xp);
    decide_dots<<<192, 256, 0, stream>>>(xp, kpw, cw1, dots);
    decide_final<<<1, 64, 0, stream>>>(dots, ck, cb1, cw2, cb2, flags);
    big_gemm<<<dim3(16, 6, 2), 256, 0, stream>>>(xhi, xlo, swh, swl, ubh, Hp, Pp);
    route_kernel<<<512, 256, 0, stream>>>(Hp, sb1, sw2, sb2, pos,
                                          flags, route, clist);
    crit_gemm<<<dim3(16, 16), 256, 0, stream>>>(xhi, lwh, lb, clist, flags, out);
    stage2_kernel<<<128, 256, 0, stream>>>(1, x, Pp, v4, v12, v40, v128,
                                           cd, flags, route, out);
    stage2_kernel<<<128, 256, 0, stream>>>(2, x, Pp, v4, v12, v40, v128,
                                           cd, flags, route, out);
}